// Round 1
// baseline (1335.754 us; speedup 1.0000x reference)
//
#include <hip/hip_runtime.h>
#include <math.h>

#define Hh 720
#define Ww 1280
#define Bb 2
#define HW (Hh*Ww)
#define OUTC 18
#define EPSF 1e-7f

// ---------------------------------------------------------------------------
// Kernel 1: bidirectional bilinear forward splat (softsplat numerators+denoms)
// acc layout inside d_out (per batch, 18 planes of HW):
//   ch 6..8  : sum(img0*w*bilin)  (f01 numerator)   ch 16 : sum(w*bilin) f01
//   ch 9..11 : sum(img1*w*bilin)  (f10 numerator)   ch 17 : sum(w*bilin) f10
// f01 uses flow1_ = 0.5*flow1 (x-disp = ch1, y-disp = ch0 after [:, ::-1]), w=exp(z1)
// f10 uses flow0_ = 0.5*flow0, w=exp(z0)
// ---------------------------------------------------------------------------
__global__ __launch_bounds__(256) void splat_kernel(
    const float* __restrict__ img0, const float* __restrict__ img1,
    const float* __restrict__ flow0, const float* __restrict__ flow1,
    const float* __restrict__ z0, const float* __restrict__ z1,
    float* __restrict__ out)
{
    int i = blockIdx.x * 256 + threadIdx.x;
    if (i >= Bb * HW) return;
    int b = i / HW;
    int p = i - b * HW;
    int y = p / Ww;
    int x = p - y * Ww;

#pragma unroll
    for (int d = 0; d < 2; ++d) {
        const float* img = d ? img1 : img0;
        const float* flw = d ? flow0 : flow1;
        const float* met = d ? z0 : z1;
        float* accImg = out + ((size_t)b * OUTC + (d ? 9 : 6)) * HW;
        float* accW   = out + ((size_t)b * OUTC + (d ? 17 : 16)) * HW;

        float fx = (float)x + 0.5f * flw[((size_t)b * 2 + 1) * HW + p];
        float fy = (float)y + 0.5f * flw[((size_t)b * 2 + 0) * HW + p];
        float w  = expf(met[(size_t)b * HW + p]);
        float v0 = img[((size_t)b * 3 + 0) * HW + p] * w;
        float v1 = img[((size_t)b * 3 + 1) * HW + p] * w;
        float v2 = img[((size_t)b * 3 + 2) * HW + p] * w;

        float x0f = floorf(fx), y0f = floorf(fy);
        float x1f = x0f + 1.0f, y1f = y0f + 1.0f;
        int   x0  = (int)x0f,  y0i = (int)y0f;
        float wxs[2] = { x1f - fx, fx - x0f };
        float wys[2] = { y1f - fy, fy - y0f };

#pragma unroll
        for (int cy = 0; cy < 2; ++cy) {
            int yy = y0i + cy;
            if (yy < 0 || yy >= Hh) continue;
#pragma unroll
            for (int cx = 0; cx < 2; ++cx) {
                int xx = x0 + cx;
                if (xx < 0 || xx >= Ww) continue;
                float wt = wxs[cx] * wys[cy];
                if (wt == 0.0f) continue;
                int q = yy * Ww + xx;
                atomicAdd(accImg + q,          v0 * wt);
                atomicAdd(accImg + HW + q,     v1 * wt);
                atomicAdd(accImg + 2 * HW + q, v2 * wt);
                atomicAdd(accW + q,            w  * wt);
            }
        }
    }
}

// ---------------------------------------------------------------------------
// Kernel 2: erosion (k x k min, SAME padding) of the raw weight sums.
// morph_open(s/(s+eps)) == f(morph_open(s)) because x/(x+eps) is monotone.
// Eroded results are parked in out ch12 (f01) / ch13 (f10); those channels are
// rewritten with flow0_ by the final flow kernel.
// ---------------------------------------------------------------------------
__global__ __launch_bounds__(256) void erode_kernel(float* __restrict__ out,
                                                    const int* __restrict__ kptr)
{
    int i = blockIdx.x * 256 + threadIdx.x;
    if (i >= Bb * HW) return;
    int b = i / HW;
    int p = i - b * HW;
    int y = p / Ww;
    int x = p - y * Ww;
    int k = *kptr;

    const float* s01 = out + ((size_t)b * OUTC + 16) * HW;
    const float* s10 = out + ((size_t)b * OUTC + 17) * HW;
    float* er01 = out + ((size_t)b * OUTC + 12) * HW;
    float* er10 = out + ((size_t)b * OUTC + 13) * HW;

    if (k <= 0) { er01[p] = s01[p]; er10[p] = s10[p]; return; }

    int lo = (k - 1) / 2, hi = (k - 1) - lo;
    float m0 = INFINITY, m1 = INFINITY;
    for (int dy = -lo; dy <= hi; ++dy) {
        int yy = y + dy;
        if (yy < 0 || yy >= Hh) continue;
        for (int dx = -lo; dx <= hi; ++dx) {
            int xx = x + dx;
            if (xx < 0 || xx >= Ww) continue;
            int q = yy * Ww + xx;
            m0 = fminf(m0, s01[q]);
            m1 = fminf(m1, s10[q]);
        }
    }
    er01[p] = m0;
    er10[p] = m1;
}

// ---------------------------------------------------------------------------
// Kernel 3: dilation of eroded weight sums + normalization + blend.
// Reads own-pixel acc (ch6..11,16,17) and er neighborhoods (ch12/13);
// writes ch0..11, 16, 17. Never writes ch12..15 (no cross-thread race).
// ---------------------------------------------------------------------------
__global__ __launch_bounds__(256) void fuse_kernel(float* __restrict__ out,
                                                   const int* __restrict__ kptr)
{
    int i = blockIdx.x * 256 + threadIdx.x;
    if (i >= Bb * HW) return;
    int b = i / HW;
    int p = i - b * HW;
    int y = p / Ww;
    int x = p - y * Ww;
    int k = *kptr;

    const float* er01 = out + ((size_t)b * OUTC + 12) * HW;
    const float* er10 = out + ((size_t)b * OUTC + 13) * HW;

    float o0, o1;
    if (k <= 0) {
        o0 = er01[p];
        o1 = er10[p];
    } else {
        int lo = (k - 1) / 2, hi = (k - 1) - lo;
        o0 = -INFINITY; o1 = -INFINITY;
        for (int dy = -lo; dy <= hi; ++dy) {
            int yy = y + dy;
            if (yy < 0 || yy >= Hh) continue;
            for (int dx = -lo; dx <= hi; ++dx) {
                int xx = x + dx;
                if (xx < 0 || xx >= Ww) continue;
                int q = yy * Ww + xx;
                o0 = fmaxf(o0, er01[q]);
                o1 = fmaxf(o1, er10[q]);
            }
        }
    }

    float m01 = o0 / (o0 + EPSF);
    float m10 = o1 / (o1 + EPSF);

    float* ob = out + (size_t)b * OUTC * HW;
    float s01 = ob[(size_t)16 * HW + p];
    float s10 = ob[(size_t)17 * HW + p];
    float d01 = s01 + EPSF;
    float d10 = s10 + EPSF;

#pragma unroll
    for (int c = 0; c < 3; ++c) {
        float f01i = ob[((size_t)6 + c) * HW + p] / d01;
        float f10i = ob[((size_t)9 + c) * HW + p] / d10;
        float base0 = m01 * f01i + (1.0f - m01) * f10i;
        float base1 = m10 * f10i + (1.0f - m10) * f01i;
        ob[((size_t)0 + c) * HW + p] = base0;
        ob[((size_t)3 + c) * HW + p] = base1;
        ob[((size_t)6 + c) * HW + p] = f01i;
        ob[((size_t)9 + c) * HW + p] = f10i;
    }
    ob[(size_t)16 * HW + p] = m01;
    ob[(size_t)17 * HW + p] = m10;
}

// ---------------------------------------------------------------------------
// Kernel 4: write scaled flows into ch12..15 (overwrites the parked erosions).
// ---------------------------------------------------------------------------
__global__ __launch_bounds__(256) void flow_kernel(const float* __restrict__ flow0,
                                                   const float* __restrict__ flow1,
                                                   float* __restrict__ out)
{
    int i = blockIdx.x * 256 + threadIdx.x;
    if (i >= Bb * 4 * HW) return;
    int b = i / (4 * HW);
    int r = i - b * 4 * HW;
    int c = r / HW;
    int p = r - c * HW;
    float v = (c < 2) ? 0.5f * flow0[((size_t)b * 2 + c) * HW + p]
                      : 0.5f * flow1[((size_t)b * 2 + (c - 2)) * HW + p];
    out[((size_t)b * OUTC + 12 + c) * HW + p] = v;
}

extern "C" void kernel_launch(void* const* d_in, const int* in_sizes, int n_in,
                              void* d_out, int out_size, void* d_ws, size_t ws_size,
                              hipStream_t stream) {
    const float* img0  = (const float*)d_in[0];
    const float* img1  = (const float*)d_in[1];
    const float* flow0 = (const float*)d_in[2];
    const float* flow1 = (const float*)d_in[3];
    const float* z0    = (const float*)d_in[4];
    const float* z1    = (const float*)d_in[5];
    const int*   kptr  = (const int*)d_in[6];
    float* out = (float*)d_out;

    // zero the 8 accumulator planes (ch6..11 contiguous, ch16..17 contiguous)
    for (int b = 0; b < Bb; ++b) {
        hipMemsetAsync(out + ((size_t)b * OUTC + 6) * HW, 0, (size_t)6 * HW * sizeof(float), stream);
        hipMemsetAsync(out + ((size_t)b * OUTC + 16) * HW, 0, (size_t)2 * HW * sizeof(float), stream);
    }

    int n = Bb * HW;
    int blocks = (n + 255) / 256;
    splat_kernel<<<blocks, 256, 0, stream>>>(img0, img1, flow0, flow1, z0, z1, out);
    erode_kernel<<<blocks, 256, 0, stream>>>(out, kptr);
    fuse_kernel<<<blocks, 256, 0, stream>>>(out, kptr);
    int n4 = Bb * 4 * HW;
    flow_kernel<<<(n4 + 255) / 256, 256, 0, stream>>>(flow0, flow1, out);
}

// Round 4
// 592.054 us; speedup vs baseline: 2.2561x; 2.2561x over previous
//
#include <hip/hip_runtime.h>
#include <math.h>

#define Hh 720
#define Ww 1280
#define Bb 2
#define HW (Hh*Ww)
#define OUTC 18
#define EPSF 1e-7f

// Tile geometry for the LDS-accumulated scatter. A source with |dx|,|dy| <= DMAX
// has corner offsets in [-2, +3] (x0 = floor(x+dx)-x in [-2,2], x1 = x0+1), so a
// halo of 2 left / 3 right suffices. Sources with larger flow (P ~ 1e-4) take
// the direct global-atomic path inside the same kernel.
#define DMAX 2.0f
#define TW 32
#define TH 8
#define HALO_L 2
#define HALO_R 3
#define LW (TW + HALO_L + HALO_R)   // 37
#define LH (TH + HALO_L + HALO_R)   // 13
#define LCELL (LW*LH)               // 481

// ---------------------------------------------------------------------------
// LDS-tiled bidirectional splat. Per-corner semantics IDENTICAL to the proven
// R1 atomic splat; only the accumulation hierarchy changed (LDS tile window +
// one atomic flush per cell instead of 4 global atomics per source corner).
// acc planes in d_out: ch6..8 + ch16 = f01 (img0 warped by 0.5*flow1, w=exp(z1)),
//                      ch9..11 + ch17 = f10 (img1 warped by 0.5*flow0, w=exp(z0)).
// Requires the 8 acc planes pre-zeroed (memsets in kernel_launch).
// ---------------------------------------------------------------------------
__global__ __launch_bounds__(256) void splat_tile_kernel(
    const float* __restrict__ img0, const float* __restrict__ img1,
    const float* __restrict__ flow0, const float* __restrict__ flow1,
    const float* __restrict__ z0, const float* __restrict__ z1,
    float* __restrict__ out)
{
    __shared__ float acc[2][4][LH][LW];   // [dir][ch: v0,v1,v2,w][y][x]

    // zero LDS
    float* af = &acc[0][0][0][0];
    for (int c = threadIdx.x; c < 2 * 4 * LCELL; c += 256) af[c] = 0.0f;
    __syncthreads();

    const int tileX0 = blockIdx.x * TW;
    const int tileY0 = blockIdx.y * TH;
    const int b      = blockIdx.z;
    const int lx = threadIdx.x % TW;
    const int ly = threadIdx.x / TW;
    const int x  = tileX0 + lx;
    const int y  = tileY0 + ly;
    const int p  = y * Ww + x;

    for (int d = 0; d < 2; ++d) {
        const float* img = d ? img1 : img0;
        const float* flw = d ? flow0 : flow1;
        const float* met = d ? z0 : z1;

        float dx = 0.5f * flw[((size_t)b * 2 + 1) * HW + p];  // x-disp = flow ch1
        float dy = 0.5f * flw[((size_t)b * 2 + 0) * HW + p];  // y-disp = flow ch0
        float fx = (float)x + dx;
        float fy = (float)y + dy;
        float w  = expf(met[(size_t)b * HW + p]);
        float v0 = img[((size_t)b * 3 + 0) * HW + p] * w;
        float v1 = img[((size_t)b * 3 + 1) * HW + p] * w;
        float v2 = img[((size_t)b * 3 + 2) * HW + p] * w;

        float x0f = floorf(fx), y0f = floorf(fy);
        float x1f = x0f + 1.0f, y1f = y0f + 1.0f;
        int   x0  = (int)x0f,  y0i = (int)y0f;
        float wxs[2] = { x1f - fx, fx - x0f };
        float wys[2] = { y1f - fy, fy - y0f };

        const bool local = (fabsf(dx) <= DMAX) && (fabsf(dy) <= DMAX);

        float* accImg = out + ((size_t)b * OUTC + (d ? 9 : 6)) * HW;
        float* accW   = out + ((size_t)b * OUTC + (d ? 17 : 16)) * HW;

#pragma unroll
        for (int cy = 0; cy < 2; ++cy) {
            int yy = y0i + cy;
            if (yy < 0 || yy >= Hh) continue;
#pragma unroll
            for (int cx = 0; cx < 2; ++cx) {
                int xx = x0 + cx;
                if (xx < 0 || xx >= Ww) continue;
                float wt = wxs[cx] * wys[cy];
                if (wt == 0.0f) continue;
                if (local) {
                    int cxl = xx - tileX0 + HALO_L;   // in [0, 36]
                    int cyl = yy - tileY0 + HALO_L;   // in [0, 12]
                    atomicAdd(&acc[d][0][cyl][cxl], v0 * wt);
                    atomicAdd(&acc[d][1][cyl][cxl], v1 * wt);
                    atomicAdd(&acc[d][2][cyl][cxl], v2 * wt);
                    atomicAdd(&acc[d][3][cyl][cxl], w  * wt);
                } else {
                    int q = yy * Ww + xx;
                    atomicAdd(accImg + q,          v0 * wt);
                    atomicAdd(accImg + HW + q,     v1 * wt);
                    atomicAdd(accImg + 2 * HW + q, v2 * wt);
                    atomicAdd(accW + q,            w  * wt);
                }
            }
        }
    }
    __syncthreads();

    // flush LDS window to global accumulators (skip all-zero cells: every
    // contribution adds w*wt > 0 to the w-plane, so w==0 <=> untouched cell)
    for (int c = threadIdx.x; c < LCELL; c += 256) {
        int cyl = c / LW, cxl = c - cyl * LW;
        int gx = tileX0 + cxl - HALO_L;
        int gy = tileY0 + cyl - HALO_L;
        if (gx < 0 || gx >= Ww || gy < 0 || gy >= Hh) continue;
        size_t q = (size_t)gy * Ww + gx;
#pragma unroll
        for (int d = 0; d < 2; ++d) {
            float ws = acc[d][3][cyl][cxl];
            if (ws != 0.0f) {
                float* accImg = out + ((size_t)b * OUTC + (d ? 9 : 6)) * HW;
                atomicAdd(accImg + q,          acc[d][0][cyl][cxl]);
                atomicAdd(accImg + HW + q,     acc[d][1][cyl][cxl]);
                atomicAdd(accImg + 2 * HW + q, acc[d][2][cyl][cxl]);
                atomicAdd(out + ((size_t)b * OUTC + (d ? 17 : 16)) * HW + q, ws);
            }
        }
    }
}

// ---------------------------------------------------------------------------
// R1-proven full-2D erosion of raw weight sums: ch16/17 -> ch12/13.
// morph_open(s/(s+eps)) == f(morph_open(s)) since x/(x+eps) is monotone.
// ---------------------------------------------------------------------------
__global__ __launch_bounds__(256) void erode_kernel(float* __restrict__ out,
                                                    const int* __restrict__ kptr)
{
    int i = blockIdx.x * 256 + threadIdx.x;
    if (i >= Bb * HW) return;
    int b = i / HW;
    int p = i - b * HW;
    int y = p / Ww;
    int x = p - y * Ww;
    int k = *kptr;

    const float* s01 = out + ((size_t)b * OUTC + 16) * HW;
    const float* s10 = out + ((size_t)b * OUTC + 17) * HW;
    float* er01 = out + ((size_t)b * OUTC + 12) * HW;
    float* er10 = out + ((size_t)b * OUTC + 13) * HW;

    if (k <= 0) { er01[p] = s01[p]; er10[p] = s10[p]; return; }

    int lo = (k - 1) / 2, hi = (k - 1) - lo;
    float m0 = INFINITY, m1 = INFINITY;
    for (int dy = -lo; dy <= hi; ++dy) {
        int yy = y + dy;
        if (yy < 0 || yy >= Hh) continue;
        for (int dx = -lo; dx <= hi; ++dx) {
            int xx = x + dx;
            if (xx < 0 || xx >= Ww) continue;
            int q = yy * Ww + xx;
            m0 = fminf(m0, s01[q]);
            m1 = fminf(m1, s10[q]);
        }
    }
    er01[p] = m0;
    er10[p] = m1;
}

// ---------------------------------------------------------------------------
// R1-proven fuse: full-2D dilation of ch12/13 -> opened weight sum; mask =
// o/(o+eps); normalize numerators; blend. Writes ch0..11, 16, 17 only.
// ---------------------------------------------------------------------------
__global__ __launch_bounds__(256) void fuse_kernel(float* __restrict__ out,
                                                   const int* __restrict__ kptr)
{
    int i = blockIdx.x * 256 + threadIdx.x;
    if (i >= Bb * HW) return;
    int b = i / HW;
    int p = i - b * HW;
    int y = p / Ww;
    int x = p - y * Ww;
    int k = *kptr;

    const float* er01 = out + ((size_t)b * OUTC + 12) * HW;
    const float* er10 = out + ((size_t)b * OUTC + 13) * HW;

    float o0, o1;
    if (k <= 0) {
        o0 = er01[p];
        o1 = er10[p];
    } else {
        int lo = (k - 1) / 2, hi = (k - 1) - lo;
        o0 = -INFINITY; o1 = -INFINITY;
        for (int dy = -lo; dy <= hi; ++dy) {
            int yy = y + dy;
            if (yy < 0 || yy >= Hh) continue;
            for (int dx = -lo; dx <= hi; ++dx) {
                int xx = x + dx;
                if (xx < 0 || xx >= Ww) continue;
                int q = yy * Ww + xx;
                o0 = fmaxf(o0, er01[q]);
                o1 = fmaxf(o1, er10[q]);
            }
        }
    }

    float m01 = o0 / (o0 + EPSF);
    float m10 = o1 / (o1 + EPSF);

    float* ob = out + (size_t)b * OUTC * HW;
    float s01 = ob[(size_t)16 * HW + p];
    float s10 = ob[(size_t)17 * HW + p];
    float d01 = s01 + EPSF;
    float d10 = s10 + EPSF;

#pragma unroll
    for (int c = 0; c < 3; ++c) {
        float f01i = ob[((size_t)6 + c) * HW + p] / d01;
        float f10i = ob[((size_t)9 + c) * HW + p] / d10;
        float base0 = m01 * f01i + (1.0f - m01) * f10i;
        float base1 = m10 * f10i + (1.0f - m10) * f01i;
        ob[((size_t)0 + c) * HW + p] = base0;
        ob[((size_t)3 + c) * HW + p] = base1;
        ob[((size_t)6 + c) * HW + p] = f01i;
        ob[((size_t)9 + c) * HW + p] = f10i;
    }
    ob[(size_t)16 * HW + p] = m01;
    ob[(size_t)17 * HW + p] = m10;
}

// ---------------------------------------------------------------------------
// Write scaled flows into ch12..15 (overwrites the parked erosions). Last.
// ---------------------------------------------------------------------------
__global__ __launch_bounds__(256) void flow_kernel(const float* __restrict__ flow0,
                                                   const float* __restrict__ flow1,
                                                   float* __restrict__ out)
{
    int i = blockIdx.x * 256 + threadIdx.x;
    if (i >= Bb * 4 * HW) return;
    int b = i / (4 * HW);
    int r = i - b * 4 * HW;
    int c = r / HW;
    int p = r - c * HW;
    float v = (c < 2) ? 0.5f * flow0[((size_t)b * 2 + c) * HW + p]
                      : 0.5f * flow1[((size_t)b * 2 + (c - 2)) * HW + p];
    out[((size_t)b * OUTC + 12 + c) * HW + p] = v;
}

extern "C" void kernel_launch(void* const* d_in, const int* in_sizes, int n_in,
                              void* d_out, int out_size, void* d_ws, size_t ws_size,
                              hipStream_t stream) {
    const float* img0  = (const float*)d_in[0];
    const float* img1  = (const float*)d_in[1];
    const float* flow0 = (const float*)d_in[2];
    const float* flow1 = (const float*)d_in[3];
    const float* z0    = (const float*)d_in[4];
    const float* z1    = (const float*)d_in[5];
    const int*   kptr  = (const int*)d_in[6];
    float* out = (float*)d_out;

    // zero the 8 accumulator planes (ch6..11 contiguous, ch16..17 contiguous)
    for (int b = 0; b < Bb; ++b) {
        hipMemsetAsync(out + ((size_t)b * OUTC + 6) * HW, 0, (size_t)6 * HW * sizeof(float), stream);
        hipMemsetAsync(out + ((size_t)b * OUTC + 16) * HW, 0, (size_t)2 * HW * sizeof(float), stream);
    }

    int n = Bb * HW;
    int blocks = (n + 255) / 256;

    dim3 sgrid(Ww / TW, Hh / TH, Bb);   // 40 x 90 x 2
    splat_tile_kernel<<<sgrid, 256, 0, stream>>>(img0, img1, flow0, flow1, z0, z1, out);
    erode_kernel<<<blocks, 256, 0, stream>>>(out, kptr);
    fuse_kernel<<<blocks, 256, 0, stream>>>(out, kptr);
    int n4 = Bb * 4 * HW;
    flow_kernel<<<(n4 + 255) / 256, 256, 0, stream>>>(flow0, flow1, out);
}